// Round 2
// baseline (565.097 us; speedup 1.0000x reference)
//
#include <hip/hip_runtime.h>
#include <hip/hip_bf16.h>

#define NN 100000
#define NE 1600000
#define NT 6250          // 16-row MFMA tiles over N
#define SCAN_NB 98       // ceil(NN/1024)

using f32x4  = __attribute__((ext_vector_type(4))) float;
using bf16x8 = __attribute__((ext_vector_type(8))) short;   // 8 bf16 in 4 VGPRs

__device__ __forceinline__ unsigned short f2bf(float f){
  union { float f; unsigned int i; } v; v.f = f;
  unsigned int r = v.i + 0x7fffu + ((v.i >> 16) & 1u);   // RNE
  return (unsigned short)(r >> 16);
}
__device__ __forceinline__ float bf2f(unsigned short u){
  union { unsigned int i; float f; } v; v.i = ((unsigned int)u) << 16; return v.f;
}
// bf16 frag from bf16 row (16B load)
__device__ __forceinline__ bf16x8 ld_frag(const unsigned short* p){
  return __builtin_bit_cast(bf16x8, *reinterpret_cast<const int4*>(p));
}
// bf16 frag from fp32 row (two 16B loads + cvt)
__device__ __forceinline__ bf16x8 ld_frag_f32(const float* p){
  f32x4 a = *reinterpret_cast<const f32x4*>(p);
  f32x4 b = *reinterpret_cast<const f32x4*>(p + 4);
  bf16x8 r;
  r[0]=(short)f2bf(a[0]); r[1]=(short)f2bf(a[1]); r[2]=(short)f2bf(a[2]); r[3]=(short)f2bf(a[3]);
  r[4]=(short)f2bf(b[0]); r[5]=(short)f2bf(b[1]); r[6]=(short)f2bf(b[2]); r[7]=(short)f2bf(b[3]);
  return r;
}
__device__ __forceinline__ f32x4 mfma16(bf16x8 a, bf16x8 b, f32x4 c){
  return __builtin_amdgcn_mfma_f32_16x16x32_bf16(a, b, c, 0, 0, 0);
}
__device__ __forceinline__ float sigm(float v){ return 1.0f / (1.0f + __expf(-v)); }
__device__ __forceinline__ float tanh_fast(float v){ return 1.0f - 2.0f / (__expf(2.0f*v) + 1.0f); }

// ---- convert all weight matrices fp32 -> bf16 (w_conv also transposed to [n][k]) ----
__global__ void k_prep(const float* __restrict__ wconv, const float* __restrict__ gwih,
                       const float* __restrict__ gwhh, const float* __restrict__ lwih,
                       const float* __restrict__ lwhh, const float* __restrict__ linw,
                       unsigned short* __restrict__ wT,   unsigned short* __restrict__ bgih,
                       unsigned short* __restrict__ bghh, unsigned short* __restrict__ blih,
                       unsigned short* __restrict__ blhh, unsigned short* __restrict__ blin){
  int t = blockIdx.x*blockDim.x + threadIdx.x;
  int stride = gridDim.x*blockDim.x;
  for(int i=t;i< 4096;i+=stride){ int k=i>>6, n=i&63; wT[n*64+k]=f2bf(wconv[i]); }
  for(int i=t;i<12288;i+=stride) bgih[i]=f2bf(gwih[i]);
  for(int i=t;i<12288;i+=stride) bghh[i]=f2bf(gwhh[i]);
  for(int i=t;i<16384;i+=stride) blih[i]=f2bf(lwih[i]);
  for(int i=t;i<16384;i+=stride) blhh[i]=f2bf(lwhh[i]);
  for(int i=t;i<  768;i+=stride) blin[i]=f2bf(linw[i]);
}

// ---- m = x @ w_conv  (bf16 out), MFMA 16x16x32, one wave per 16-row tile ----
__global__ __launch_bounds__(256) void k_mgemm(const float* __restrict__ x,
                                               const unsigned short* __restrict__ wT,
                                               unsigned short* __restrict__ m){
  int wv = (int)((blockIdx.x*256u + threadIdx.x) >> 6);
  if(wv >= NT) return;
  int lane = threadIdx.x & 63, q = lane >> 4, ln = lane & 15;
  int row0 = wv * 16;
  bf16x8 A[2], B[4][2];
  #pragma unroll
  for(int kf = 0; kf < 2; kf++){
    A[kf] = ld_frag_f32(&x[(size_t)(row0 + ln)*64 + kf*32 + q*8]);
    #pragma unroll
    for(int nt = 0; nt < 4; nt++) B[nt][kf] = ld_frag(&wT[(nt*16 + ln)*64 + kf*32 + q*8]);
  }
  #pragma unroll
  for(int nt = 0; nt < 4; nt++){
    f32x4 C = {0.f,0.f,0.f,0.f};
    #pragma unroll
    for(int kf = 0; kf < 2; kf++) C = mfma16(A[kf], B[nt][kf], C);
    #pragma unroll
    for(int r = 0; r < 4; r++) m[(size_t)(row0 + q*4 + r)*64 + nt*16 + ln] = f2bf(C[r]);
  }
}

// ---- edge histogram ----
__global__ void k_hist(const int* __restrict__ ei, int* __restrict__ cnt){
  int e = blockIdx.x*blockDim.x + threadIdx.x;
  if(e < NE) atomicAdd(&cnt[ei[NE + e]], 1);
}

// ---- exclusive scan of cnt -> off ----
__global__ __launch_bounds__(256) void k_scan1(const int* __restrict__ cnt, int* __restrict__ part, int* __restrict__ bsum){
  __shared__ int sh[256];
  int b = blockIdx.x, t = threadIdx.x;
  int base = b*1024;
  int v[4]; int s = 0;
  #pragma unroll
  for(int u = 0; u < 4; u++){ int idx = base + t*4 + u; v[u] = (idx < NN) ? cnt[idx] : 0; s += v[u]; }
  sh[t] = s; __syncthreads();
  for(int ofs = 1; ofs < 256; ofs <<= 1){
    int xv = (t >= ofs) ? sh[t-ofs] : 0; __syncthreads();
    sh[t] += xv; __syncthreads();
  }
  int run = sh[t] - s;
  if(t == 255) bsum[b] = sh[255];
  #pragma unroll
  for(int u = 0; u < 4; u++){ int idx = base + t*4 + u; if(idx < NN) part[idx] = run; run += v[u]; }
}
__global__ void k_scan2(int* __restrict__ bsum){
  __shared__ int sh[128];
  int t = threadIdx.x;
  int v = (t < SCAN_NB) ? bsum[t] : 0;
  sh[t] = v; __syncthreads();
  for(int ofs = 1; ofs < 128; ofs <<= 1){
    int xv = (t >= ofs) ? sh[t-ofs] : 0; __syncthreads();
    sh[t] += xv; __syncthreads();
  }
  if(t < SCAN_NB) bsum[t] = sh[t] - v;
}
__global__ void k_scan3(const int* __restrict__ bsum, int* __restrict__ off, int* __restrict__ cur){
  int i = blockIdx.x*blockDim.x + threadIdx.x;
  if(i < NN){ int o = off[i] + bsum[i >> 10]; off[i] = o; cur[i] = o; }
}

// ---- counting-sort scatter: edges grouped by dst ----
__global__ void k_scatter(const int* __restrict__ ei, const float* __restrict__ ew,
                          int* __restrict__ cur, int* __restrict__ ssrc, float* __restrict__ sew){
  int e = blockIdx.x*blockDim.x + threadIdx.x;
  if(e >= NE) return;
  int d = ei[NE + e];
  int p = atomicAdd(&cur[d], 1);
  ssrc[p] = ei[e];
  sew[p]  = ew[e];
}

// ---- SpMM: one wave per dst node, mean-aggregate; agg in bf16 ----
__global__ __launch_bounds__(256) void k_spmm(const unsigned short* __restrict__ m,
                                              const int* __restrict__ ssrc, const float* __restrict__ sew,
                                              const int* __restrict__ off, const int* __restrict__ cnt,
                                              unsigned short* __restrict__ agg){
  int d = (int)((blockIdx.x*256u + threadIdx.x) >> 6);
  if(d >= NN) return;
  int lane = threadIdx.x & 63;
  int k = cnt[d], st = off[d];
  float acc = 0.f;
  int i = 0;
  while(i < k){
    int rem = k - i;
    int take = rem < 64 ? rem : 64;
    int s = 0; float w = 0.f;
    if(lane < take){ s = ssrc[st + i + lane]; w = sew[st + i + lane]; }
    for(int j = 0; j < take; j++){
      int   sj = __shfl(s, j, 64);
      float wj = __shfl(w, j, 64);
      acc += wj * bf2f(m[(size_t)sj*64 + lane]);
    }
    i += take;
  }
  float inv = 1.0f / fmaxf((float)k, 1.0f);
  agg[(size_t)d*64 + lane] = f2bf(acc * inv);
}

// ---- GRUCell(agg, x) -> h_tilde (bf16), fused MFMA ----
__global__ __launch_bounds__(256) void k_gru(const unsigned short* __restrict__ agg,
    const float* __restrict__ x,
    const unsigned short* __restrict__ w_ih, const unsigned short* __restrict__ w_hh,
    const float* __restrict__ b_ih, const float* __restrict__ b_hh,
    unsigned short* __restrict__ ht){
  int wv = (int)((blockIdx.x*256u + threadIdx.x) >> 6);
  if(wv >= NT) return;
  int lane = threadIdx.x & 63, q = lane >> 4, ln = lane & 15;
  int row0 = wv * 16;
  bf16x8 Aa[2], Ax[2];
  #pragma unroll
  for(int kf = 0; kf < 2; kf++){
    Aa[kf] = ld_frag(&agg[(size_t)(row0 + ln)*64 + kf*32 + q*8]);
    Ax[kf] = ld_frag_f32(&x[(size_t)(row0 + ln)*64 + kf*32 + q*8]);
  }
  #pragma unroll
  for(int g = 0; g < 4; g++){
    f32x4 ir={0,0,0,0}, hr={0,0,0,0}, iz={0,0,0,0}, hz={0,0,0,0}, in_={0,0,0,0}, hn={0,0,0,0};
    #pragma unroll
    for(int kf = 0; kf < 2; kf++){
      ir  = mfma16(Aa[kf], ld_frag(&w_ih[((g    )*16 + ln)*64 + kf*32 + q*8]), ir );
      iz  = mfma16(Aa[kf], ld_frag(&w_ih[((g + 4)*16 + ln)*64 + kf*32 + q*8]), iz );
      in_ = mfma16(Aa[kf], ld_frag(&w_ih[((g + 8)*16 + ln)*64 + kf*32 + q*8]), in_);
      hr  = mfma16(Ax[kf], ld_frag(&w_hh[((g    )*16 + ln)*64 + kf*32 + q*8]), hr );
      hz  = mfma16(Ax[kf], ld_frag(&w_hh[((g + 4)*16 + ln)*64 + kf*32 + q*8]), hz );
      hn  = mfma16(Ax[kf], ld_frag(&w_hh[((g + 8)*16 + ln)*64 + kf*32 + q*8]), hn );
    }
    float bir = b_ih[(g    )*16 + ln], bhr = b_hh[(g    )*16 + ln];
    float biz = b_ih[(g + 4)*16 + ln], bhz = b_hh[(g + 4)*16 + ln];
    float bin = b_ih[(g + 8)*16 + ln], bhn = b_hh[(g + 8)*16 + ln];
    #pragma unroll
    for(int r = 0; r < 4; r++){
      int row = row0 + q*4 + r, col = g*16 + ln;
      float rr = sigm(ir[r] + bir + hr[r] + bhr);
      float zz = sigm(iz[r] + biz + hz[r] + bhz);
      float nn = tanh_fast(in_[r] + bin + rr*(hn[r] + bhn));
      float xv = x[(size_t)row*64 + col];
      ht[(size_t)row*64 + col] = f2bf((1.0f - zz)*nn + zz*xv);
    }
  }
}

// ---- LSTM step + relu + Linear, fused; fp32 outputs ----
__global__ __launch_bounds__(256) void k_lstm(const unsigned short* __restrict__ ht,
    const float* __restrict__ h0, const float* __restrict__ c0,
    const unsigned short* __restrict__ w_ih, const unsigned short* __restrict__ w_hh,
    const float* __restrict__ b_ih, const float* __restrict__ b_hh,
    const unsigned short* __restrict__ lin_w, const float* __restrict__ lin_b,
    float* __restrict__ out, float* __restrict__ h1o, float* __restrict__ c1o){
  __shared__ __align__(16) unsigned short relu_sh[4][16*72];   // stride 72 bf16 = 144B rows (9x16B)
  int wid  = threadIdx.x >> 6;
  int wv   = (int)((blockIdx.x*256u + threadIdx.x) >> 6);
  int lane = threadIdx.x & 63, q = lane >> 4, ln = lane & 15;
  bool act = wv < NT;
  int row0 = wv * 16;
  if(act){
    bf16x8 Ah[2], A0[2];
    #pragma unroll
    for(int kf = 0; kf < 2; kf++){
      Ah[kf] = ld_frag(&ht[(size_t)(row0 + ln)*64 + kf*32 + q*8]);
      A0[kf] = ld_frag_f32(&h0[(size_t)(row0 + ln)*64 + kf*32 + q*8]);
    }
    #pragma unroll
    for(int g = 0; g < 4; g++){
      f32x4 gi={0,0,0,0}, gf={0,0,0,0}, gg={0,0,0,0}, go={0,0,0,0};
      #pragma unroll
      for(int kf = 0; kf < 2; kf++){
        gi = mfma16(Ah[kf], ld_frag(&w_ih[((g     )*16 + ln)*64 + kf*32 + q*8]), gi);
        gf = mfma16(Ah[kf], ld_frag(&w_ih[((g +  4)*16 + ln)*64 + kf*32 + q*8]), gf);
        gg = mfma16(Ah[kf], ld_frag(&w_ih[((g +  8)*16 + ln)*64 + kf*32 + q*8]), gg);
        go = mfma16(Ah[kf], ld_frag(&w_ih[((g + 12)*16 + ln)*64 + kf*32 + q*8]), go);
        gi = mfma16(A0[kf], ld_frag(&w_hh[((g     )*16 + ln)*64 + kf*32 + q*8]), gi);
        gf = mfma16(A0[kf], ld_frag(&w_hh[((g +  4)*16 + ln)*64 + kf*32 + q*8]), gf);
        gg = mfma16(A0[kf], ld_frag(&w_hh[((g +  8)*16 + ln)*64 + kf*32 + q*8]), gg);
        go = mfma16(A0[kf], ld_frag(&w_hh[((g + 12)*16 + ln)*64 + kf*32 + q*8]), go);
      }
      float bi = b_ih[(g     )*16 + ln] + b_hh[(g     )*16 + ln];
      float bf = b_ih[(g +  4)*16 + ln] + b_hh[(g +  4)*16 + ln];
      float bg = b_ih[(g +  8)*16 + ln] + b_hh[(g +  8)*16 + ln];
      float bo = b_ih[(g + 12)*16 + ln] + b_hh[(g + 12)*16 + ln];
      #pragma unroll
      for(int r = 0; r < 4; r++){
        int row = row0 + q*4 + r, col = g*16 + ln;
        float cp = c0[(size_t)row*64 + col];
        float si = sigm(gi[r] + bi), sf = sigm(gf[r] + bf), so = sigm(go[r] + bo);
        float c1 = sf*cp + si*tanh_fast(gg[r] + bg);
        float h1 = so*tanh_fast(c1);
        c1o[(size_t)row*64 + col] = c1;
        h1o[(size_t)row*64 + col] = h1;
        relu_sh[wid][(q*4 + r)*72 + col] = f2bf(fmaxf(h1, 0.f));
      }
    }
  }
  __syncthreads();
  if(act){
    f32x4 C = {0.f,0.f,0.f,0.f};
    #pragma unroll
    for(int kf = 0; kf < 2; kf++){
      bf16x8 a = ld_frag(&relu_sh[wid][ln*72 + kf*32 + q*8]);
      bf16x8 b = {0,0,0,0,0,0,0,0};
      if(ln < 12) b = ld_frag(&lin_w[ln*64 + kf*32 + q*8]);
      C = mfma16(a, b, C);
    }
    if(ln < 12){
      float lb = lin_b[ln];
      #pragma unroll
      for(int r = 0; r < 4; r++) out[(size_t)(row0 + q*4 + r)*12 + ln] = C[r] + lb;
    }
  }
}

extern "C" void kernel_launch(void* const* d_in, const int* in_sizes, int n_in,
                              void* d_out, int out_size, void* d_ws, size_t ws_size,
                              hipStream_t stream){
  const float* x     = (const float*)d_in[0];
  const float* ew    = (const float*)d_in[1];
  const float* wconv = (const float*)d_in[2];
  const float* gwih  = (const float*)d_in[3];
  const float* gwhh  = (const float*)d_in[4];
  const float* gbih  = (const float*)d_in[5];
  const float* gbhh  = (const float*)d_in[6];
  const float* lwih  = (const float*)d_in[7];
  const float* lwhh  = (const float*)d_in[8];
  const float* lbih  = (const float*)d_in[9];
  const float* lbhh  = (const float*)d_in[10];
  const float* linw  = (const float*)d_in[11];
  const float* linb  = (const float*)d_in[12];
  const float* h0    = (const float*)d_in[13];
  const float* c0    = (const float*)d_in[14];
  const int*   ei    = (const int*)d_in[15];

  char* w = (char*)d_ws;
  size_t o = 0;
  auto alloc = [&](size_t bytes) -> void* {
    void* p = w + o; o += (bytes + 255) & ~(size_t)255; return p;
  };
  unsigned short* m    = (unsigned short*)alloc((size_t)NN*64*2);
  unsigned short* agg  = (unsigned short*)alloc((size_t)NN*64*2);
  unsigned short* htl  = (unsigned short*)alloc((size_t)NN*64*2);
  unsigned short* wT   = (unsigned short*)alloc(4096*2);
  unsigned short* bgih = (unsigned short*)alloc(12288*2);
  unsigned short* bghh = (unsigned short*)alloc(12288*2);
  unsigned short* blih = (unsigned short*)alloc(16384*2);
  unsigned short* blhh = (unsigned short*)alloc(16384*2);
  unsigned short* blin = (unsigned short*)alloc(768*2);
  int* cnt  = (int*)alloc((size_t)NN*4);
  int* off  = (int*)alloc((size_t)NN*4);
  int* cur  = (int*)alloc((size_t)NN*4);
  int* bsum = (int*)alloc(512);
  int* ssrc = (int*)alloc((size_t)NE*4);
  float* sew = (float*)alloc((size_t)NE*4);

  float* outp = (float*)d_out;
  float* h1o  = outp + (size_t)NN*12;
  float* c1o  = h1o + (size_t)NN*64;

  hipMemsetAsync(cnt, 0, (size_t)NN*4, stream);
  k_prep   <<<32, 256, 0, stream>>>(wconv, gwih, gwhh, lwih, lwhh, linw,
                                    wT, bgih, bghh, blih, blhh, blin);
  k_mgemm  <<<(NT + 3)/4, 256, 0, stream>>>(x, wT, m);
  k_hist   <<<(NE + 255)/256, 256, 0, stream>>>(ei, cnt);
  k_scan1  <<<SCAN_NB, 256, 0, stream>>>(cnt, off, bsum);
  k_scan2  <<<1, 128, 0, stream>>>(bsum);
  k_scan3  <<<(NN + 255)/256, 256, 0, stream>>>(bsum, off, cur);
  k_scatter<<<(NE + 255)/256, 256, 0, stream>>>(ei, ew, cur, ssrc, sew);
  k_spmm   <<<(NN + 3)/4, 256, 0, stream>>>(m, ssrc, sew, off, cnt, agg);
  k_gru    <<<(NT + 3)/4, 256, 0, stream>>>(agg, x, bgih, bghh, gbih, gbhh, htl);
  k_lstm   <<<(NT + 3)/4, 256, 0, stream>>>(htl, h0, c0, blih, blhh, lbih, lbhh, blin, linb, outp, h1o, c1o);
}

// Round 3
// 523.349 us; speedup vs baseline: 1.0798x; 1.0798x over previous
//
#include <hip/hip_runtime.h>
#include <hip/hip_bf16.h>

#define NN 100000
#define NE 1600000
#define NT 6250          // 16-row MFMA tiles over N
#define SCAN_NB 98       // ceil(NN/1024)

using f32x4  = __attribute__((ext_vector_type(4))) float;
using bf16x8 = __attribute__((ext_vector_type(8))) short;   // 8 bf16 in 4 VGPRs

__device__ __forceinline__ unsigned short f2bf(float f){
  union { float f; unsigned int i; } v; v.f = f;
  unsigned int r = v.i + 0x7fffu + ((v.i >> 16) & 1u);   // RNE
  return (unsigned short)(r >> 16);
}
__device__ __forceinline__ float bf2f(unsigned short u){
  union { unsigned int i; float f; } v; v.i = ((unsigned int)u) << 16; return v.f;
}
__device__ __forceinline__ bf16x8 ld_frag(const unsigned short* p){
  return __builtin_bit_cast(bf16x8, *reinterpret_cast<const int4*>(p));
}
__device__ __forceinline__ f32x4 mfma16(bf16x8 a, bf16x8 b, f32x4 c){
  return __builtin_amdgcn_mfma_f32_16x16x32_bf16(a, b, c, 0, 0, 0);
}
__device__ __forceinline__ float sigm(float v){ return 1.0f / (1.0f + __expf(-v)); }
__device__ __forceinline__ float tanh_fast(float v){ return 1.0f - 2.0f / (__expf(2.0f*v) + 1.0f); }

// ---- x -> bf16, weight matrices fp32 -> bf16 ----
__global__ void k_prep(const float* __restrict__ x,    const float* __restrict__ gwhh,
                       const float* __restrict__ lwih, const float* __restrict__ lwhh,
                       const float* __restrict__ linw,
                       unsigned short* __restrict__ xb,   unsigned short* __restrict__ bghh,
                       unsigned short* __restrict__ blih, unsigned short* __restrict__ blhh,
                       unsigned short* __restrict__ blin){
  int t = blockIdx.x*blockDim.x + threadIdx.x;
  int stride = gridDim.x*blockDim.x;
  for(int i = t; i < NN*64/4; i += stride){
    f32x4 v = *reinterpret_cast<const f32x4*>(x + (size_t)i*4);
    unsigned short o0 = f2bf(v[0]), o1 = f2bf(v[1]), o2 = f2bf(v[2]), o3 = f2bf(v[3]);
    *reinterpret_cast<uint2*>(xb + (size_t)i*4) =
        make_uint2((unsigned)o0 | ((unsigned)o1 << 16), (unsigned)o2 | ((unsigned)o3 << 16));
  }
  for(int i=t;i<12288;i+=stride) bghh[i]=f2bf(gwhh[i]);
  for(int i=t;i<16384;i+=stride) blih[i]=f2bf(lwih[i]);
  for(int i=t;i<16384;i+=stride) blhh[i]=f2bf(lwhh[i]);
  for(int i=t;i<  768;i+=stride) blin[i]=f2bf(linw[i]);
}

// ---- Wc[o][k] = sum_j w_conv[k][j] * gru_w_ih[o][j]  (fused conv+GRU-ih weight) ----
__global__ void k_wcomb(const float* __restrict__ wconv, const float* __restrict__ gwih,
                        unsigned short* __restrict__ Bc){
  int t = blockIdx.x*blockDim.x + threadIdx.x;   // 12288 = 192*64
  if(t >= 12288) return;
  int o = t >> 6, k = t & 63;
  float s = 0.f;
  #pragma unroll 8
  for(int j = 0; j < 64; j++) s += wconv[k*64 + j] * gwih[o*64 + j];
  Bc[t] = f2bf(s);
}

// ---- edge histogram ----
__global__ void k_hist(const int* __restrict__ ei, int* __restrict__ cnt){
  int e = blockIdx.x*blockDim.x + threadIdx.x;
  if(e < NE) atomicAdd(&cnt[ei[NE + e]], 1);
}

// ---- exclusive scan of cnt -> off ----
__global__ __launch_bounds__(256) void k_scan1(const int* __restrict__ cnt, int* __restrict__ part, int* __restrict__ bsum){
  __shared__ int sh[256];
  int b = blockIdx.x, t = threadIdx.x;
  int base = b*1024;
  int v[4]; int s = 0;
  #pragma unroll
  for(int u = 0; u < 4; u++){ int idx = base + t*4 + u; v[u] = (idx < NN) ? cnt[idx] : 0; s += v[u]; }
  sh[t] = s; __syncthreads();
  for(int ofs = 1; ofs < 256; ofs <<= 1){
    int xv = (t >= ofs) ? sh[t-ofs] : 0; __syncthreads();
    sh[t] += xv; __syncthreads();
  }
  int run = sh[t] - s;
  if(t == 255) bsum[b] = sh[255];
  #pragma unroll
  for(int u = 0; u < 4; u++){ int idx = base + t*4 + u; if(idx < NN) part[idx] = run; run += v[u]; }
}
__global__ void k_scan2(int* __restrict__ bsum){
  __shared__ int sh[128];
  int t = threadIdx.x;
  int v = (t < SCAN_NB) ? bsum[t] : 0;
  sh[t] = v; __syncthreads();
  for(int ofs = 1; ofs < 128; ofs <<= 1){
    int xv = (t >= ofs) ? sh[t-ofs] : 0; __syncthreads();
    sh[t] += xv; __syncthreads();
  }
  if(t < SCAN_NB) bsum[t] = sh[t] - v;
}
__global__ void k_scan3(const int* __restrict__ bsum, int* __restrict__ off, int* __restrict__ cur){
  int i = blockIdx.x*blockDim.x + threadIdx.x;
  if(i < NN){ int o = off[i] + bsum[i >> 10]; off[i] = o; cur[i] = o; }
}

// ---- counting-sort scatter: one packed 8B record per edge ----
__global__ void k_scatter(const int* __restrict__ ei, const float* __restrict__ ew,
                          int* __restrict__ cur, int2* __restrict__ spk){
  int e = blockIdx.x*blockDim.x + threadIdx.x;
  if(e >= NE) return;
  int d = ei[NE + e];
  int p = atomicAdd(&cur[d], 1);
  int2 rec; rec.x = ei[e]; rec.y = __float_as_int(ew[e]);
  spk[p] = rec;
}

// ---- SpMM on raw x (bf16): one wave per dst node, mean-aggregate ----
__global__ __launch_bounds__(256) void k_spmm(const unsigned short* __restrict__ xb,
                                              const int2* __restrict__ spk,
                                              const int* __restrict__ off, const int* __restrict__ cnt,
                                              unsigned short* __restrict__ agg){
  int d = (int)((blockIdx.x*256u + threadIdx.x) >> 6);
  if(d >= NN) return;
  int lane = threadIdx.x & 63;
  int k = cnt[d], st = off[d];
  float a0 = 0.f, a1 = 0.f, a2 = 0.f, a3 = 0.f;
  int i = 0;
  while(i < k){
    int rem = k - i;
    int take = rem < 64 ? rem : 64;
    int s = 0; float w = 0.f;
    if(lane < take){ int2 r = spk[st + i + lane]; s = r.x; w = __int_as_float(r.y); }
    int j = 0;
    for(; j + 4 <= take; j += 4){
      int   s0 = __shfl(s, j, 64),   s1 = __shfl(s, j+1, 64),   s2 = __shfl(s, j+2, 64),   s3 = __shfl(s, j+3, 64);
      float w0 = __shfl(w, j, 64),   w1 = __shfl(w, j+1, 64),   w2 = __shfl(w, j+2, 64),   w3 = __shfl(w, j+3, 64);
      float v0 = bf2f(xb[(size_t)s0*64 + lane]);
      float v1 = bf2f(xb[(size_t)s1*64 + lane]);
      float v2 = bf2f(xb[(size_t)s2*64 + lane]);
      float v3 = bf2f(xb[(size_t)s3*64 + lane]);
      a0 += w0*v0; a1 += w1*v1; a2 += w2*v2; a3 += w3*v3;
    }
    for(; j < take; j++){
      int   sj = __shfl(s, j, 64);
      float wj = __shfl(w, j, 64);
      a0 += wj * bf2f(xb[(size_t)sj*64 + lane]);
    }
    i += take;
  }
  float acc = (a0 + a1) + (a2 + a3);
  float inv = 1.0f / fmaxf((float)k, 1.0f);
  agg[(size_t)d*64 + lane] = f2bf(acc * inv);
}

// ---- GRUCell: gi = agg_raw @ Wc + b_ih ; gh = x @ w_hh.T + b_hh ----
__global__ __launch_bounds__(256) void k_gru(const unsigned short* __restrict__ agg,
    const unsigned short* __restrict__ xb,
    const unsigned short* __restrict__ Bc, const unsigned short* __restrict__ w_hh,
    const float* __restrict__ b_ih, const float* __restrict__ b_hh,
    unsigned short* __restrict__ ht){
  int wv = (int)((blockIdx.x*256u + threadIdx.x) >> 6);
  if(wv >= NT) return;
  int lane = threadIdx.x & 63, q = lane >> 4, ln = lane & 15;
  int row0 = wv * 16;
  bf16x8 Aa[2], Ax[2];
  #pragma unroll
  for(int kf = 0; kf < 2; kf++){
    Aa[kf] = ld_frag(&agg[(size_t)(row0 + ln)*64 + kf*32 + q*8]);
    Ax[kf] = ld_frag(&xb [(size_t)(row0 + ln)*64 + kf*32 + q*8]);
  }
  #pragma unroll
  for(int g = 0; g < 4; g++){
    f32x4 ir={0,0,0,0}, hr={0,0,0,0}, iz={0,0,0,0}, hz={0,0,0,0}, in_={0,0,0,0}, hn={0,0,0,0};
    #pragma unroll
    for(int kf = 0; kf < 2; kf++){
      ir  = mfma16(Aa[kf], ld_frag(&Bc  [((g    )*16 + ln)*64 + kf*32 + q*8]), ir );
      iz  = mfma16(Aa[kf], ld_frag(&Bc  [((g + 4)*16 + ln)*64 + kf*32 + q*8]), iz );
      in_ = mfma16(Aa[kf], ld_frag(&Bc  [((g + 8)*16 + ln)*64 + kf*32 + q*8]), in_);
      hr  = mfma16(Ax[kf], ld_frag(&w_hh[((g    )*16 + ln)*64 + kf*32 + q*8]), hr );
      hz  = mfma16(Ax[kf], ld_frag(&w_hh[((g + 4)*16 + ln)*64 + kf*32 + q*8]), hz );
      hn  = mfma16(Ax[kf], ld_frag(&w_hh[((g + 8)*16 + ln)*64 + kf*32 + q*8]), hn );
    }
    float bir = b_ih[(g    )*16 + ln], bhr = b_hh[(g    )*16 + ln];
    float biz = b_ih[(g + 4)*16 + ln], bhz = b_hh[(g + 4)*16 + ln];
    float bin = b_ih[(g + 8)*16 + ln], bhn = b_hh[(g + 8)*16 + ln];
    #pragma unroll
    for(int r = 0; r < 4; r++){
      int row = row0 + q*4 + r, col = g*16 + ln;
      float rr = sigm(ir[r] + bir + hr[r] + bhr);
      float zz = sigm(iz[r] + biz + hz[r] + bhz);
      float nn = tanh_fast(in_[r] + bin + rr*(hn[r] + bhn));
      float xv = bf2f(xb[(size_t)row*64 + col]);
      ht[(size_t)row*64 + col] = f2bf((1.0f - zz)*nn + zz*xv);
    }
  }
}

// ---- LSTM step + relu + Linear, fused; fp32 outputs ----
__global__ __launch_bounds__(256) void k_lstm(const unsigned short* __restrict__ ht,
    const float* __restrict__ h0, const float* __restrict__ c0,
    const unsigned short* __restrict__ w_ih, const unsigned short* __restrict__ w_hh,
    const float* __restrict__ b_ih, const float* __restrict__ b_hh,
    const unsigned short* __restrict__ lin_w, const float* __restrict__ lin_b,
    float* __restrict__ out, float* __restrict__ h1o, float* __restrict__ c1o){
  __shared__ __align__(16) unsigned short relu_sh[4][16*72];   // stride 72 bf16 = 144B rows
  int wid  = threadIdx.x >> 6;
  int wv   = (int)((blockIdx.x*256u + threadIdx.x) >> 6);
  int lane = threadIdx.x & 63, q = lane >> 4, ln = lane & 15;
  bool act = wv < NT;
  int row0 = wv * 16;
  if(act){
    bf16x8 Ah[2], A0[2];
    #pragma unroll
    for(int kf = 0; kf < 2; kf++){
      Ah[kf] = ld_frag(&ht[(size_t)(row0 + ln)*64 + kf*32 + q*8]);
      const float* p = &h0[(size_t)(row0 + ln)*64 + kf*32 + q*8];
      f32x4 a = *reinterpret_cast<const f32x4*>(p);
      f32x4 b = *reinterpret_cast<const f32x4*>(p + 4);
      bf16x8 r;
      r[0]=(short)f2bf(a[0]); r[1]=(short)f2bf(a[1]); r[2]=(short)f2bf(a[2]); r[3]=(short)f2bf(a[3]);
      r[4]=(short)f2bf(b[0]); r[5]=(short)f2bf(b[1]); r[6]=(short)f2bf(b[2]); r[7]=(short)f2bf(b[3]);
      A0[kf] = r;
    }
    #pragma unroll
    for(int g = 0; g < 4; g++){
      f32x4 gi={0,0,0,0}, gf={0,0,0,0}, gg={0,0,0,0}, go={0,0,0,0};
      #pragma unroll
      for(int kf = 0; kf < 2; kf++){
        gi = mfma16(Ah[kf], ld_frag(&w_ih[((g     )*16 + ln)*64 + kf*32 + q*8]), gi);
        gf = mfma16(Ah[kf], ld_frag(&w_ih[((g +  4)*16 + ln)*64 + kf*32 + q*8]), gf);
        gg = mfma16(Ah[kf], ld_frag(&w_ih[((g +  8)*16 + ln)*64 + kf*32 + q*8]), gg);
        go = mfma16(Ah[kf], ld_frag(&w_ih[((g + 12)*16 + ln)*64 + kf*32 + q*8]), go);
        gi = mfma16(A0[kf], ld_frag(&w_hh[((g     )*16 + ln)*64 + kf*32 + q*8]), gi);
        gf = mfma16(A0[kf], ld_frag(&w_hh[((g +  4)*16 + ln)*64 + kf*32 + q*8]), gf);
        gg = mfma16(A0[kf], ld_frag(&w_hh[((g +  8)*16 + ln)*64 + kf*32 + q*8]), gg);
        go = mfma16(A0[kf], ld_frag(&w_hh[((g + 12)*16 + ln)*64 + kf*32 + q*8]), go);
      }
      float bi = b_ih[(g     )*16 + ln] + b_hh[(g     )*16 + ln];
      float bf = b_ih[(g +  4)*16 + ln] + b_hh[(g +  4)*16 + ln];
      float bg = b_ih[(g +  8)*16 + ln] + b_hh[(g +  8)*16 + ln];
      float bo = b_ih[(g + 12)*16 + ln] + b_hh[(g + 12)*16 + ln];
      #pragma unroll
      for(int r = 0; r < 4; r++){
        int row = row0 + q*4 + r, col = g*16 + ln;
        float cp = c0[(size_t)row*64 + col];
        float si = sigm(gi[r] + bi), sf = sigm(gf[r] + bf), so = sigm(go[r] + bo);
        float c1 = sf*cp + si*tanh_fast(gg[r] + bg);
        float h1 = so*tanh_fast(c1);
        c1o[(size_t)row*64 + col] = c1;
        h1o[(size_t)row*64 + col] = h1;
        relu_sh[wid][(q*4 + r)*72 + col] = f2bf(fmaxf(h1, 0.f));
      }
    }
  }
  __syncthreads();
  if(act){
    f32x4 C = {0.f,0.f,0.f,0.f};
    #pragma unroll
    for(int kf = 0; kf < 2; kf++){
      bf16x8 a = ld_frag(&relu_sh[wid][ln*72 + kf*32 + q*8]);
      bf16x8 b = {0,0,0,0,0,0,0,0};
      if(ln < 12) b = ld_frag(&lin_w[ln*64 + kf*32 + q*8]);
      C = mfma16(a, b, C);
    }
    if(ln < 12){
      float lb = lin_b[ln];
      #pragma unroll
      for(int r = 0; r < 4; r++) out[(size_t)(row0 + q*4 + r)*12 + ln] = C[r] + lb;
    }
  }
}

extern "C" void kernel_launch(void* const* d_in, const int* in_sizes, int n_in,
                              void* d_out, int out_size, void* d_ws, size_t ws_size,
                              hipStream_t stream){
  const float* x     = (const float*)d_in[0];
  const float* ew    = (const float*)d_in[1];
  const float* wconv = (const float*)d_in[2];
  const float* gwih  = (const float*)d_in[3];
  const float* gwhh  = (const float*)d_in[4];
  const float* gbih  = (const float*)d_in[5];
  const float* gbhh  = (const float*)d_in[6];
  const float* lwih  = (const float*)d_in[7];
  const float* lwhh  = (const float*)d_in[8];
  const float* lbih  = (const float*)d_in[9];
  const float* lbhh  = (const float*)d_in[10];
  const float* linw  = (const float*)d_in[11];
  const float* linb  = (const float*)d_in[12];
  const float* h0    = (const float*)d_in[13];
  const float* c0    = (const float*)d_in[14];
  const int*   ei    = (const int*)d_in[15];

  char* w = (char*)d_ws;
  size_t o = 0;
  auto alloc = [&](size_t bytes) -> void* {
    void* p = w + o; o += (bytes + 255) & ~(size_t)255; return p;
  };
  unsigned short* xb   = (unsigned short*)alloc((size_t)NN*64*2);
  unsigned short* agg  = (unsigned short*)alloc((size_t)NN*64*2);
  unsigned short* htl  = (unsigned short*)alloc((size_t)NN*64*2);
  unsigned short* Bc   = (unsigned short*)alloc(12288*2);
  unsigned short* bghh = (unsigned short*)alloc(12288*2);
  unsigned short* blih = (unsigned short*)alloc(16384*2);
  unsigned short* blhh = (unsigned short*)alloc(16384*2);
  unsigned short* blin = (unsigned short*)alloc(768*2);
  int* cnt  = (int*)alloc((size_t)NN*4);
  int* off  = (int*)alloc((size_t)NN*4);
  int* cur  = (int*)alloc((size_t)NN*4);
  int* bsum = (int*)alloc(512);
  int2* spk = (int2*)alloc((size_t)NE*8);

  float* outp = (float*)d_out;
  float* h1o  = outp + (size_t)NN*12;
  float* c1o  = h1o + (size_t)NN*64;

  hipMemsetAsync(cnt, 0, (size_t)NN*4, stream);
  k_prep   <<<512, 256, 0, stream>>>(x, gwhh, lwih, lwhh, linw, xb, bghh, blih, blhh, blin);
  k_wcomb  <<<48, 256, 0, stream>>>(wconv, gwih, Bc);
  k_hist   <<<(NE + 255)/256, 256, 0, stream>>>(ei, cnt);
  k_scan1  <<<SCAN_NB, 256, 0, stream>>>(cnt, off, bsum);
  k_scan2  <<<1, 128, 0, stream>>>(bsum);
  k_scan3  <<<(NN + 255)/256, 256, 0, stream>>>(bsum, off, cur);
  k_scatter<<<(NE + 255)/256, 256, 0, stream>>>(ei, ew, cur, spk);
  k_spmm   <<<(NN + 3)/4, 256, 0, stream>>>(xb, spk, off, cnt, agg);
  k_gru    <<<(NT + 3)/4, 256, 0, stream>>>(agg, xb, Bc, bghh, gbih, gbhh, htl);
  k_lstm   <<<(NT + 3)/4, 256, 0, stream>>>(htl, h0, c0, blih, blhh, lbih, lbhh, blin, linb, outp, h1o, c1o);
}

// Round 4
// 431.728 us; speedup vs baseline: 1.3089x; 1.2122x over previous
//
#include <hip/hip_runtime.h>
#include <hip/hip_bf16.h>

#define NN 100000
#define NE 1600000
#define NT 6250          // 16-row MFMA tiles over N
#define SCAN_NB 98       // ceil(NN/1024)

using f32x4  = __attribute__((ext_vector_type(4))) float;
using bf16x8 = __attribute__((ext_vector_type(8))) short;   // 8 bf16 in 4 VGPRs

__device__ __forceinline__ unsigned short f2bf(float f){
  union { float f; unsigned int i; } v; v.f = f;
  unsigned int r = v.i + 0x7fffu + ((v.i >> 16) & 1u);   // RNE
  return (unsigned short)(r >> 16);
}
__device__ __forceinline__ float bf2f(unsigned short u){
  union { unsigned int i; float f; } v; v.i = ((unsigned int)u) << 16; return v.f;
}
__device__ __forceinline__ bf16x8 ld_frag(const unsigned short* p){
  return __builtin_bit_cast(bf16x8, *reinterpret_cast<const int4*>(p));
}
__device__ __forceinline__ f32x4 mfma16(bf16x8 a, bf16x8 b, f32x4 c){
  return __builtin_amdgcn_mfma_f32_16x16x32_bf16(a, b, c, 0, 0, 0);
}
__device__ __forceinline__ float sigm(float v){ return 1.0f / (1.0f + __expf(-v)); }
__device__ __forceinline__ float tanh_fast(float v){ return 1.0f - 2.0f / (__expf(2.0f*v) + 1.0f); }

// ---- x -> bf16, weights fp32 -> bf16, fused conv*gru_ih weight ----
__global__ void k_prep(const float* __restrict__ x,    const float* __restrict__ gwhh,
                       const float* __restrict__ lwih, const float* __restrict__ lwhh,
                       const float* __restrict__ linw, const float* __restrict__ wconv,
                       const float* __restrict__ gwih,
                       unsigned short* __restrict__ xb,   unsigned short* __restrict__ bghh,
                       unsigned short* __restrict__ blih, unsigned short* __restrict__ blhh,
                       unsigned short* __restrict__ blin, unsigned short* __restrict__ Bc){
  int t = blockIdx.x*blockDim.x + threadIdx.x;
  int stride = gridDim.x*blockDim.x;
  for(int i = t; i < NN*64/4; i += stride){
    f32x4 v = *reinterpret_cast<const f32x4*>(x + (size_t)i*4);
    unsigned short o0 = f2bf(v[0]), o1 = f2bf(v[1]), o2 = f2bf(v[2]), o3 = f2bf(v[3]);
    *reinterpret_cast<uint2*>(xb + (size_t)i*4) =
        make_uint2((unsigned)o0 | ((unsigned)o1 << 16), (unsigned)o2 | ((unsigned)o3 << 16));
  }
  for(int i=t;i<12288;i+=stride) bghh[i]=f2bf(gwhh[i]);
  for(int i=t;i<16384;i+=stride) blih[i]=f2bf(lwih[i]);
  for(int i=t;i<16384;i+=stride) blhh[i]=f2bf(lwhh[i]);
  for(int i=t;i<  768;i+=stride) blin[i]=f2bf(linw[i]);
  if(t < 12288){                      // Bc[o][k] = sum_j wconv[k][j]*gwih[o][j]
    int o = t >> 6, k = t & 63;
    float s = 0.f;
    #pragma unroll 8
    for(int j = 0; j < 64; j++) s += wconv[k*64 + j] * gwih[o*64 + j];
    Bc[t] = f2bf(s);
  }
}

// ---- edge histogram + per-edge rank (atomic return value) ----
__global__ void k_hist(const int* __restrict__ ei, int* __restrict__ cnt,
                       unsigned short* __restrict__ rank){
  int e = blockIdx.x*blockDim.x + threadIdx.x;
  if(e < NE){
    int r = atomicAdd(&cnt[ei[NE + e]], 1);
    rank[e] = (unsigned short)r;
  }
}

// ---- exclusive scan of cnt -> off ----
__global__ __launch_bounds__(256) void k_scan1(const int* __restrict__ cnt, int* __restrict__ part, int* __restrict__ bsum){
  __shared__ int sh[256];
  int b = blockIdx.x, t = threadIdx.x;
  int base = b*1024;
  int v[4]; int s = 0;
  #pragma unroll
  for(int u = 0; u < 4; u++){ int idx = base + t*4 + u; v[u] = (idx < NN) ? cnt[idx] : 0; s += v[u]; }
  sh[t] = s; __syncthreads();
  for(int ofs = 1; ofs < 256; ofs <<= 1){
    int xv = (t >= ofs) ? sh[t-ofs] : 0; __syncthreads();
    sh[t] += xv; __syncthreads();
  }
  int run = sh[t] - s;
  if(t == 255) bsum[b] = sh[255];
  #pragma unroll
  for(int u = 0; u < 4; u++){ int idx = base + t*4 + u; if(idx < NN) part[idx] = run; run += v[u]; }
}
__global__ void k_scan2(int* __restrict__ bsum){
  __shared__ int sh[128];
  int t = threadIdx.x;
  int v = (t < SCAN_NB) ? bsum[t] : 0;
  sh[t] = v; __syncthreads();
  for(int ofs = 1; ofs < 128; ofs <<= 1){
    int xv = (t >= ofs) ? sh[t-ofs] : 0; __syncthreads();
    sh[t] += xv; __syncthreads();
  }
  if(t < SCAN_NB) bsum[t] = sh[t] - v;
}
__global__ void k_scan3(const int* __restrict__ bsum, int* __restrict__ off){
  int i = blockIdx.x*blockDim.x + threadIdx.x;
  if(i < NN) off[i] += bsum[i >> 10];
}

// ---- counting-sort scatter: atomic-free, pos = off[dst] + rank ----
__global__ void k_scatter(const int* __restrict__ ei, const float* __restrict__ ew,
                          const int* __restrict__ off, const unsigned short* __restrict__ rank,
                          int2* __restrict__ spk){
  int e = blockIdx.x*blockDim.x + threadIdx.x;
  if(e >= NE) return;
  int d = ei[NE + e];
  int p = off[d] + (int)rank[e];
  int2 rec; rec.x = ei[e]; rec.y = __float_as_int(ew[e]);
  spk[p] = rec;
}

// ---- SpMM on raw x (bf16): one wave per dst node, mean-aggregate ----
__global__ __launch_bounds__(256) void k_spmm(const unsigned short* __restrict__ xb,
                                              const int2* __restrict__ spk,
                                              const int* __restrict__ off, const int* __restrict__ cnt,
                                              unsigned short* __restrict__ agg){
  int d = (int)((blockIdx.x*256u + threadIdx.x) >> 6);
  if(d >= NN) return;
  int lane = threadIdx.x & 63;
  int k = cnt[d], st = off[d];
  float a0 = 0.f, a1 = 0.f, a2 = 0.f, a3 = 0.f;
  int i = 0;
  while(i < k){
    int rem = k - i;
    int take = rem < 64 ? rem : 64;
    int s = 0; float w = 0.f;
    if(lane < take){ int2 r = spk[st + i + lane]; s = r.x; w = __int_as_float(r.y); }
    int j = 0;
    for(; j + 4 <= take; j += 4){
      int   s0 = __shfl(s, j, 64),   s1 = __shfl(s, j+1, 64),   s2 = __shfl(s, j+2, 64),   s3 = __shfl(s, j+3, 64);
      float w0 = __shfl(w, j, 64),   w1 = __shfl(w, j+1, 64),   w2 = __shfl(w, j+2, 64),   w3 = __shfl(w, j+3, 64);
      float v0 = bf2f(xb[(size_t)s0*64 + lane]);
      float v1 = bf2f(xb[(size_t)s1*64 + lane]);
      float v2 = bf2f(xb[(size_t)s2*64 + lane]);
      float v3 = bf2f(xb[(size_t)s3*64 + lane]);
      a0 += w0*v0; a1 += w1*v1; a2 += w2*v2; a3 += w3*v3;
    }
    for(; j < take; j++){
      int   sj = __shfl(s, j, 64);
      float wj = __shfl(w, j, 64);
      a0 += wj * bf2f(xb[(size_t)sj*64 + lane]);
    }
    i += take;
  }
  float acc = (a0 + a1) + (a2 + a3);
  float inv = 1.0f / fmaxf((float)k, 1.0f);
  agg[(size_t)d*64 + lane] = f2bf(acc * inv);
}

// ---- fused GRU + LSTM + relu + Linear; h_tilde stays in LDS ----
__global__ __launch_bounds__(256) void k_cell(const unsigned short* __restrict__ agg,
    const unsigned short* __restrict__ xb,
    const unsigned short* __restrict__ Bc,   const unsigned short* __restrict__ g_whh,
    const float* __restrict__ g_bih,         const float* __restrict__ g_bhh,
    const float* __restrict__ h0,            const float* __restrict__ c0,
    const unsigned short* __restrict__ l_wih,const unsigned short* __restrict__ l_whh,
    const float* __restrict__ l_bih,         const float* __restrict__ l_bhh,
    const unsigned short* __restrict__ lin_w,const float* __restrict__ lin_b,
    float* __restrict__ out, float* __restrict__ h1o, float* __restrict__ c1o){
  __shared__ __align__(16) unsigned short tile_sh[4][16*72];   // stride 72 bf16 = 144B rows
  int wid  = threadIdx.x >> 6;
  int wv   = (int)((blockIdx.x*256u + threadIdx.x) >> 6);
  int lane = threadIdx.x & 63, q = lane >> 4, ln = lane & 15;
  bool act = wv < NT;
  int row0 = wv * 16;

  // ---- phase 1: GRU -> h_tilde into LDS ----
  if(act){
    bf16x8 Aa[2], Ax[2];
    #pragma unroll
    for(int kf = 0; kf < 2; kf++){
      Aa[kf] = ld_frag(&agg[(size_t)(row0 + ln)*64 + kf*32 + q*8]);
      Ax[kf] = ld_frag(&xb [(size_t)(row0 + ln)*64 + kf*32 + q*8]);
    }
    #pragma unroll
    for(int g = 0; g < 4; g++){
      f32x4 ir={0,0,0,0}, hr={0,0,0,0}, iz={0,0,0,0}, hz={0,0,0,0}, in_={0,0,0,0}, hn={0,0,0,0};
      #pragma unroll
      for(int kf = 0; kf < 2; kf++){
        ir  = mfma16(Aa[kf], ld_frag(&Bc   [((g    )*16 + ln)*64 + kf*32 + q*8]), ir );
        iz  = mfma16(Aa[kf], ld_frag(&Bc   [((g + 4)*16 + ln)*64 + kf*32 + q*8]), iz );
        in_ = mfma16(Aa[kf], ld_frag(&Bc   [((g + 8)*16 + ln)*64 + kf*32 + q*8]), in_);
        hr  = mfma16(Ax[kf], ld_frag(&g_whh[((g    )*16 + ln)*64 + kf*32 + q*8]), hr );
        hz  = mfma16(Ax[kf], ld_frag(&g_whh[((g + 4)*16 + ln)*64 + kf*32 + q*8]), hz );
        hn  = mfma16(Ax[kf], ld_frag(&g_whh[((g + 8)*16 + ln)*64 + kf*32 + q*8]), hn );
      }
      float bir = g_bih[(g    )*16 + ln], bhr = g_bhh[(g    )*16 + ln];
      float biz = g_bih[(g + 4)*16 + ln], bhz = g_bhh[(g + 4)*16 + ln];
      float bin = g_bih[(g + 8)*16 + ln], bhn = g_bhh[(g + 8)*16 + ln];
      #pragma unroll
      for(int r = 0; r < 4; r++){
        int row = row0 + q*4 + r, col = g*16 + ln;
        float rr = sigm(ir[r] + bir + hr[r] + bhr);
        float zz = sigm(iz[r] + biz + hz[r] + bhz);
        float nn = tanh_fast(in_[r] + bin + rr*(hn[r] + bhn));
        float xv = bf2f(xb[(size_t)row*64 + col]);
        tile_sh[wid][(q*4 + r)*72 + col] = f2bf((1.0f - zz)*nn + zz*xv);
      }
    }
  }
  __syncthreads();

  // ---- phase 2: LSTM from LDS h_tilde ----
  if(act){
    bf16x8 Ah[2], A0[2];
    #pragma unroll
    for(int kf = 0; kf < 2; kf++){
      Ah[kf] = ld_frag(&tile_sh[wid][ln*72 + kf*32 + q*8]);
      const float* p = &h0[(size_t)(row0 + ln)*64 + kf*32 + q*8];
      f32x4 a = *reinterpret_cast<const f32x4*>(p);
      f32x4 b = *reinterpret_cast<const f32x4*>(p + 4);
      bf16x8 r;
      r[0]=(short)f2bf(a[0]); r[1]=(short)f2bf(a[1]); r[2]=(short)f2bf(a[2]); r[3]=(short)f2bf(a[3]);
      r[4]=(short)f2bf(b[0]); r[5]=(short)f2bf(b[1]); r[6]=(short)f2bf(b[2]); r[7]=(short)f2bf(b[3]);
      A0[kf] = r;
    }
    f32x4 c1v[4], h1v[4];   // per-g results kept to defer LDS overwrite
    #pragma unroll
    for(int g = 0; g < 4; g++){
      f32x4 gi={0,0,0,0}, gf={0,0,0,0}, gg={0,0,0,0}, go={0,0,0,0};
      #pragma unroll
      for(int kf = 0; kf < 2; kf++){
        gi = mfma16(Ah[kf], ld_frag(&l_wih[((g     )*16 + ln)*64 + kf*32 + q*8]), gi);
        gf = mfma16(Ah[kf], ld_frag(&l_wih[((g +  4)*16 + ln)*64 + kf*32 + q*8]), gf);
        gg = mfma16(Ah[kf], ld_frag(&l_wih[((g +  8)*16 + ln)*64 + kf*32 + q*8]), gg);
        go = mfma16(Ah[kf], ld_frag(&l_wih[((g + 12)*16 + ln)*64 + kf*32 + q*8]), go);
        gi = mfma16(A0[kf], ld_frag(&l_whh[((g     )*16 + ln)*64 + kf*32 + q*8]), gi);
        gf = mfma16(A0[kf], ld_frag(&l_whh[((g +  4)*16 + ln)*64 + kf*32 + q*8]), gf);
        gg = mfma16(A0[kf], ld_frag(&l_whh[((g +  8)*16 + ln)*64 + kf*32 + q*8]), gg);
        go = mfma16(A0[kf], ld_frag(&l_whh[((g + 12)*16 + ln)*64 + kf*32 + q*8]), go);
      }
      float bi = l_bih[(g     )*16 + ln] + l_bhh[(g     )*16 + ln];
      float bf = l_bih[(g +  4)*16 + ln] + l_bhh[(g +  4)*16 + ln];
      float bg = l_bih[(g +  8)*16 + ln] + l_bhh[(g +  8)*16 + ln];
      float bo = l_bih[(g + 12)*16 + ln] + l_bhh[(g + 12)*16 + ln];
      #pragma unroll
      for(int r = 0; r < 4; r++){
        int row = row0 + q*4 + r, col = g*16 + ln;
        float cp = c0[(size_t)row*64 + col];
        float si = sigm(gi[r] + bi), sf = sigm(gf[r] + bf), so = sigm(go[r] + bo);
        float c1 = sf*cp + si*tanh_fast(gg[r] + bg);
        float h1 = so*tanh_fast(c1);
        c1v[g][r] = c1; h1v[g][r] = h1;
        c1o[(size_t)row*64 + col] = c1;
        h1o[(size_t)row*64 + col] = h1;
      }
    }
    __syncthreads();   // all Ah reads done block-wide before relu overwrites
    #pragma unroll
    for(int g = 0; g < 4; g++)
      #pragma unroll
      for(int r = 0; r < 4; r++)
        tile_sh[wid][(q*4 + r)*72 + g*16 + ln] = f2bf(fmaxf(h1v[g][r], 0.f));
  } else {
    __syncthreads();
  }
  __syncthreads();

  // ---- phase 3: relu @ lin_w ----
  if(act){
    f32x4 C = {0.f,0.f,0.f,0.f};
    #pragma unroll
    for(int kf = 0; kf < 2; kf++){
      bf16x8 a = ld_frag(&tile_sh[wid][ln*72 + kf*32 + q*8]);
      bf16x8 b = {0,0,0,0,0,0,0,0};
      if(ln < 12) b = ld_frag(&lin_w[ln*64 + kf*32 + q*8]);
      C = mfma16(a, b, C);
    }
    if(ln < 12){
      float lb = lin_b[ln];
      #pragma unroll
      for(int r = 0; r < 4; r++) out[(size_t)(row0 + q*4 + r)*12 + ln] = C[r] + lb;
    }
  }
}

extern "C" void kernel_launch(void* const* d_in, const int* in_sizes, int n_in,
                              void* d_out, int out_size, void* d_ws, size_t ws_size,
                              hipStream_t stream){
  const float* x     = (const float*)d_in[0];
  const float* ew    = (const float*)d_in[1];
  const float* wconv = (const float*)d_in[2];
  const float* gwih  = (const float*)d_in[3];
  const float* gwhh  = (const float*)d_in[4];
  const float* gbih  = (const float*)d_in[5];
  const float* gbhh  = (const float*)d_in[6];
  const float* lwih  = (const float*)d_in[7];
  const float* lwhh  = (const float*)d_in[8];
  const float* lbih  = (const float*)d_in[9];
  const float* lbhh  = (const float*)d_in[10];
  const float* linw  = (const float*)d_in[11];
  const float* linb  = (const float*)d_in[12];
  const float* h0    = (const float*)d_in[13];
  const float* c0    = (const float*)d_in[14];
  const int*   ei    = (const int*)d_in[15];

  char* w = (char*)d_ws;
  size_t o = 0;
  auto alloc = [&](size_t bytes) -> void* {
    void* p = w + o; o += (bytes + 255) & ~(size_t)255; return p;
  };
  unsigned short* xb   = (unsigned short*)alloc((size_t)NN*64*2);
  unsigned short* agg  = (unsigned short*)alloc((size_t)NN*64*2);
  unsigned short* Bc   = (unsigned short*)alloc(12288*2);
  unsigned short* bghh = (unsigned short*)alloc(12288*2);
  unsigned short* blih = (unsigned short*)alloc(16384*2);
  unsigned short* blhh = (unsigned short*)alloc(16384*2);
  unsigned short* blin = (unsigned short*)alloc(768*2);
  int* cnt  = (int*)alloc((size_t)NN*4);
  int* off  = (int*)alloc((size_t)NN*4);
  int* bsum = (int*)alloc(512);
  unsigned short* rank = (unsigned short*)alloc((size_t)NE*2);
  int2* spk = (int2*)alloc((size_t)NE*8);

  float* outp = (float*)d_out;
  float* h1o  = outp + (size_t)NN*12;
  float* c1o  = h1o + (size_t)NN*64;

  hipMemsetAsync(cnt, 0, (size_t)NN*4, stream);
  k_prep   <<<512, 256, 0, stream>>>(x, gwhh, lwih, lwhh, linw, wconv, gwih,
                                     xb, bghh, blih, blhh, blin, Bc);
  k_hist   <<<(NE + 255)/256, 256, 0, stream>>>(ei, cnt, rank);
  k_scan1  <<<SCAN_NB, 256, 0, stream>>>(cnt, off, bsum);
  k_scan2  <<<1, 128, 0, stream>>>(bsum);
  k_scan3  <<<(NN + 255)/256, 256, 0, stream>>>(bsum, off);
  k_scatter<<<(NE + 255)/256, 256, 0, stream>>>(ei, ew, off, rank, spk);
  k_spmm   <<<(NN + 3)/4, 256, 0, stream>>>(xb, spk, off, cnt, agg);
  k_cell   <<<(NT + 3)/4, 256, 0, stream>>>(agg, xb, Bc, bghh, gbih, gbhh,
                                            h0, c0, blih, blhh, lbih, lbhh,
                                            blin, linb, outp, h1o, c1o);
}

// Round 5
// 388.893 us; speedup vs baseline: 1.4531x; 1.1101x over previous
//
#include <hip/hip_runtime.h>
#include <hip/hip_bf16.h>

#define NN 100000
#define NE 1600000
#define NT 6250          // 16-row MFMA tiles over N
#define SCAN_NB 98       // ceil(NN/1024)
#define GRU_NBLK 768     // 3 blocks/CU (48 KB LDS)
#define LSTM_NBLK 512    // 2 blocks/CU (75 KB LDS)

using f32x4  = __attribute__((ext_vector_type(4))) float;
using bf16x8 = __attribute__((ext_vector_type(8))) short;   // 8 bf16 in 4 VGPRs

__device__ __forceinline__ unsigned short f2bf(float f){
  union { float f; unsigned int i; } v; v.f = f;
  unsigned int r = v.i + 0x7fffu + ((v.i >> 16) & 1u);   // RNE
  return (unsigned short)(r >> 16);
}
__device__ __forceinline__ float bf2f(unsigned short u){
  union { unsigned int i; float f; } v; v.i = ((unsigned int)u) << 16; return v.f;
}
__device__ __forceinline__ bf16x8 ld_frag(const unsigned short* p){
  return __builtin_bit_cast(bf16x8, *reinterpret_cast<const int4*>(p));
}
__device__ __forceinline__ f32x4 mfma16(bf16x8 a, bf16x8 b, f32x4 c){
  return __builtin_amdgcn_mfma_f32_16x16x32_bf16(a, b, c, 0, 0, 0);
}
__device__ __forceinline__ float sigm(float v){ return 1.0f / (1.0f + __expf(-v)); }
__device__ __forceinline__ float tanh_fast(float v){ return 1.0f - 2.0f / (__expf(2.0f*v) + 1.0f); }

// ---- x -> bf16, weights fp32 -> bf16, fused conv*gru_ih weight ----
__global__ void k_prep(const float* __restrict__ x,    const float* __restrict__ gwhh,
                       const float* __restrict__ lwih, const float* __restrict__ lwhh,
                       const float* __restrict__ linw, const float* __restrict__ wconv,
                       const float* __restrict__ gwih,
                       unsigned short* __restrict__ xb,   unsigned short* __restrict__ bghh,
                       unsigned short* __restrict__ blih, unsigned short* __restrict__ blhh,
                       unsigned short* __restrict__ blin, unsigned short* __restrict__ Bc){
  int t = blockIdx.x*blockDim.x + threadIdx.x;
  int stride = gridDim.x*blockDim.x;
  for(int i = t; i < NN*64/4; i += stride){
    f32x4 v = *reinterpret_cast<const f32x4*>(x + (size_t)i*4);
    unsigned short o0 = f2bf(v[0]), o1 = f2bf(v[1]), o2 = f2bf(v[2]), o3 = f2bf(v[3]);
    *reinterpret_cast<uint2*>(xb + (size_t)i*4) =
        make_uint2((unsigned)o0 | ((unsigned)o1 << 16), (unsigned)o2 | ((unsigned)o3 << 16));
  }
  for(int i=t;i<12288;i+=stride) bghh[i]=f2bf(gwhh[i]);
  for(int i=t;i<16384;i+=stride) blih[i]=f2bf(lwih[i]);
  for(int i=t;i<16384;i+=stride) blhh[i]=f2bf(lwhh[i]);
  for(int i=t;i<  768;i+=stride) blin[i]=f2bf(linw[i]);
  if(t < 12288){                      // Bc[o][k] = sum_j wconv[k][j]*gwih[o][j]
    int o = t >> 6, k = t & 63;
    float s = 0.f;
    #pragma unroll 8
    for(int j = 0; j < 64; j++) s += wconv[k*64 + j] * gwih[o*64 + j];
    Bc[t] = f2bf(s);
  }
}

// ---- edge histogram + per-edge rank (atomic return value) ----
__global__ void k_hist(const int* __restrict__ ei, int* __restrict__ cnt,
                       unsigned short* __restrict__ rank){
  int e = blockIdx.x*blockDim.x + threadIdx.x;
  if(e < NE){
    int r = atomicAdd(&cnt[ei[NE + e]], 1);
    rank[e] = (unsigned short)r;
  }
}

// ---- exclusive scan of cnt -> off ----
__global__ __launch_bounds__(256) void k_scan1(const int* __restrict__ cnt, int* __restrict__ part, int* __restrict__ bsum){
  __shared__ int sh[256];
  int b = blockIdx.x, t = threadIdx.x;
  int base = b*1024;
  int v[4]; int s = 0;
  #pragma unroll
  for(int u = 0; u < 4; u++){ int idx = base + t*4 + u; v[u] = (idx < NN) ? cnt[idx] : 0; s += v[u]; }
  sh[t] = s; __syncthreads();
  for(int ofs = 1; ofs < 256; ofs <<= 1){
    int xv = (t >= ofs) ? sh[t-ofs] : 0; __syncthreads();
    sh[t] += xv; __syncthreads();
  }
  int run = sh[t] - s;
  if(t == 255) bsum[b] = sh[255];
  #pragma unroll
  for(int u = 0; u < 4; u++){ int idx = base + t*4 + u; if(idx < NN) part[idx] = run; run += v[u]; }
}
__global__ void k_scan2(int* __restrict__ bsum){
  __shared__ int sh[128];
  int t = threadIdx.x;
  int v = (t < SCAN_NB) ? bsum[t] : 0;
  sh[t] = v; __syncthreads();
  for(int ofs = 1; ofs < 128; ofs <<= 1){
    int xv = (t >= ofs) ? sh[t-ofs] : 0; __syncthreads();
    sh[t] += xv; __syncthreads();
  }
  if(t < SCAN_NB) bsum[t] = sh[t] - v;
}
__global__ void k_scan3(const int* __restrict__ bsum, int* __restrict__ off){
  int i = blockIdx.x*blockDim.x + threadIdx.x;
  if(i < NN) off[i] += bsum[i >> 10];
}

// ---- counting-sort scatter: atomic-free, pos = off[dst] + rank ----
__global__ void k_scatter(const int* __restrict__ ei, const float* __restrict__ ew,
                          const int* __restrict__ off, const unsigned short* __restrict__ rank,
                          int2* __restrict__ spk){
  int e = blockIdx.x*blockDim.x + threadIdx.x;
  if(e >= NE) return;
  int d = ei[NE + e];
  int p = off[d] + (int)rank[e];
  int2 rec; rec.x = ei[e]; rec.y = __float_as_int(ew[e]);
  spk[p] = rec;
}

// ---- SpMM on raw x (bf16): one wave per dst node, mean-aggregate ----
__global__ __launch_bounds__(256) void k_spmm(const unsigned short* __restrict__ xb,
                                              const int2* __restrict__ spk,
                                              const int* __restrict__ off, const int* __restrict__ cnt,
                                              unsigned short* __restrict__ agg){
  int d = (int)((blockIdx.x*256u + threadIdx.x) >> 6);
  if(d >= NN) return;
  int lane = threadIdx.x & 63;
  int k = cnt[d], st = off[d];
  float a0 = 0.f, a1 = 0.f, a2 = 0.f, a3 = 0.f;
  int i = 0;
  while(i < k){
    int rem = k - i;
    int take = rem < 64 ? rem : 64;
    int s = 0; float w = 0.f;
    if(lane < take){ int2 r = spk[st + i + lane]; s = r.x; w = __int_as_float(r.y); }
    int j = 0;
    for(; j + 4 <= take; j += 4){
      int   s0 = __shfl(s, j, 64),   s1 = __shfl(s, j+1, 64),   s2 = __shfl(s, j+2, 64),   s3 = __shfl(s, j+3, 64);
      float w0 = __shfl(w, j, 64),   w1 = __shfl(w, j+1, 64),   w2 = __shfl(w, j+2, 64),   w3 = __shfl(w, j+3, 64);
      float v0 = bf2f(xb[(size_t)s0*64 + lane]);
      float v1 = bf2f(xb[(size_t)s1*64 + lane]);
      float v2 = bf2f(xb[(size_t)s2*64 + lane]);
      float v3 = bf2f(xb[(size_t)s3*64 + lane]);
      a0 += w0*v0; a1 += w1*v1; a2 += w2*v2; a3 += w3*v3;
    }
    for(; j < take; j++){
      int   sj = __shfl(s, j, 64);
      float wj = __shfl(w, j, 64);
      a0 += wj * bf2f(xb[(size_t)sj*64 + lane]);
    }
    i += take;
  }
  float acc = (a0 + a1) + (a2 + a3);
  float inv = 1.0f / fmaxf((float)k, 1.0f);
  agg[(size_t)d*64 + lane] = f2bf(acc * inv);
}

// ---- GRU: weights LDS-resident (fragment-swizzled), grid-stride over tiles ----
__global__ __launch_bounds__(256) void k_gru(const unsigned short* __restrict__ agg,
    const unsigned short* __restrict__ xb,
    const unsigned short* __restrict__ Bc, const unsigned short* __restrict__ g_whh,
    const float* __restrict__ g_bih, const float* __restrict__ g_bhh,
    unsigned short* __restrict__ ht){
  __shared__ __align__(16) unsigned short swA[12*2*64*8];   // Bc, frag order: 24 KB
  __shared__ __align__(16) unsigned short swB[12*2*64*8];   // g_whh: 24 KB
  for(int i = threadIdx.x; i < 12*2*64; i += 256){
    int fid = i >> 6, lane2 = i & 63;
    int gi = fid >> 1, kf = fid & 1, q2 = lane2 >> 4, ln2 = lane2 & 15;
    int src = (gi*16 + ln2)*64 + kf*32 + q2*8;
    *reinterpret_cast<int4*>(&swA[i*8]) = *reinterpret_cast<const int4*>(&Bc[src]);
    *reinterpret_cast<int4*>(&swB[i*8]) = *reinterpret_cast<const int4*>(&g_whh[src]);
  }
  __syncthreads();
  int lane = threadIdx.x & 63, q = lane >> 4, ln = lane & 15;
  int wv0 = (int)((blockIdx.x*256u + threadIdx.x) >> 6);
  for(int wv = wv0; wv < NT; wv += GRU_NBLK*4){
    int row0 = wv * 16;
    bf16x8 Aa[2], Ax[2];
    #pragma unroll
    for(int kf = 0; kf < 2; kf++){
      Aa[kf] = ld_frag(&agg[(size_t)(row0 + ln)*64 + kf*32 + q*8]);
      Ax[kf] = ld_frag(&xb [(size_t)(row0 + ln)*64 + kf*32 + q*8]);
    }
    #pragma unroll
    for(int g = 0; g < 4; g++){
      f32x4 ir={0,0,0,0}, hr={0,0,0,0}, iz={0,0,0,0}, hz={0,0,0,0}, in_={0,0,0,0}, hn={0,0,0,0};
      #pragma unroll
      for(int kf = 0; kf < 2; kf++){
        ir  = mfma16(Aa[kf], ld_frag(&swA[(((g    )*2 + kf)*64 + lane)*8]), ir );
        iz  = mfma16(Aa[kf], ld_frag(&swA[(((g + 4)*2 + kf)*64 + lane)*8]), iz );
        in_ = mfma16(Aa[kf], ld_frag(&swA[(((g + 8)*2 + kf)*64 + lane)*8]), in_);
        hr  = mfma16(Ax[kf], ld_frag(&swB[(((g    )*2 + kf)*64 + lane)*8]), hr );
        hz  = mfma16(Ax[kf], ld_frag(&swB[(((g + 4)*2 + kf)*64 + lane)*8]), hz );
        hn  = mfma16(Ax[kf], ld_frag(&swB[(((g + 8)*2 + kf)*64 + lane)*8]), hn );
      }
      float bir = g_bih[(g    )*16 + ln], bhr = g_bhh[(g    )*16 + ln];
      float biz = g_bih[(g + 4)*16 + ln], bhz = g_bhh[(g + 4)*16 + ln];
      float bin = g_bih[(g + 8)*16 + ln], bhn = g_bhh[(g + 8)*16 + ln];
      #pragma unroll
      for(int r = 0; r < 4; r++){
        int row = row0 + q*4 + r, col = g*16 + ln;
        float rr = sigm(ir[r] + bir + hr[r] + bhr);
        float zz = sigm(iz[r] + biz + hz[r] + bhz);
        float nn = tanh_fast(in_[r] + bin + rr*(hn[r] + bhn));
        float xv = bf2f(xb[(size_t)row*64 + col]);
        ht[(size_t)row*64 + col] = f2bf((1.0f - zz)*nn + zz*xv);
      }
    }
  }
}

// ---- LSTM + relu + Linear: weights LDS-resident, grid-stride over tiles ----
__global__ __launch_bounds__(256) void k_lstm(const unsigned short* __restrict__ ht,
    const float* __restrict__ h0, const float* __restrict__ c0,
    const unsigned short* __restrict__ l_wih, const unsigned short* __restrict__ l_whh,
    const float* __restrict__ l_bih, const float* __restrict__ l_bhh,
    const unsigned short* __restrict__ lin_w, const float* __restrict__ lin_b,
    float* __restrict__ out, float* __restrict__ h1o, float* __restrict__ c1o){
  __shared__ __align__(16) unsigned short swI[16*2*64*8];   // l_wih: 32 KB
  __shared__ __align__(16) unsigned short swH[16*2*64*8];   // l_whh: 32 KB
  __shared__ __align__(16) unsigned short swL[2*64*8];      // lin_w (zero-padded): 2 KB
  __shared__ __align__(16) unsigned short tile_sh[4][16*72];// relu transpose: 9 KB
  for(int i = threadIdx.x; i < 16*2*64; i += 256){
    int fid = i >> 6, lane2 = i & 63;
    int gi = fid >> 1, kf = fid & 1, q2 = lane2 >> 4, ln2 = lane2 & 15;
    int src = (gi*16 + ln2)*64 + kf*32 + q2*8;
    *reinterpret_cast<int4*>(&swI[i*8]) = *reinterpret_cast<const int4*>(&l_wih[src]);
    *reinterpret_cast<int4*>(&swH[i*8]) = *reinterpret_cast<const int4*>(&l_whh[src]);
  }
  for(int i = threadIdx.x; i < 2*64; i += 256){
    int kf = i >> 6, lane2 = i & 63, q2 = lane2 >> 4, ln2 = lane2 & 15;
    int4 v = {0,0,0,0};
    if(ln2 < 12) v = *reinterpret_cast<const int4*>(&lin_w[ln2*64 + kf*32 + q2*8]);
    *reinterpret_cast<int4*>(&swL[i*8]) = v;
  }
  __syncthreads();
  int wid = threadIdx.x >> 6;
  int lane = threadIdx.x & 63, q = lane >> 4, ln = lane & 15;
  int wv0 = blockIdx.x*4 + wid;
  const int ITER = (NT + LSTM_NBLK*4 - 1)/(LSTM_NBLK*4);
  for(int s = 0; s < ITER; s++){
    int wv = wv0 + s*LSTM_NBLK*4;
    bool act = wv < NT;
    int row0 = wv * 16;
    if(act){
      bf16x8 Ah[2], A0[2];
      #pragma unroll
      for(int kf = 0; kf < 2; kf++){
        Ah[kf] = ld_frag(&ht[(size_t)(row0 + ln)*64 + kf*32 + q*8]);
        const float* p = &h0[(size_t)(row0 + ln)*64 + kf*32 + q*8];
        f32x4 a = *reinterpret_cast<const f32x4*>(p);
        f32x4 b = *reinterpret_cast<const f32x4*>(p + 4);
        bf16x8 r;
        r[0]=(short)f2bf(a[0]); r[1]=(short)f2bf(a[1]); r[2]=(short)f2bf(a[2]); r[3]=(short)f2bf(a[3]);
        r[4]=(short)f2bf(b[0]); r[5]=(short)f2bf(b[1]); r[6]=(short)f2bf(b[2]); r[7]=(short)f2bf(b[3]);
        A0[kf] = r;
      }
      #pragma unroll
      for(int g = 0; g < 4; g++){
        f32x4 gi={0,0,0,0}, gf={0,0,0,0}, gg={0,0,0,0}, go={0,0,0,0};
        #pragma unroll
        for(int kf = 0; kf < 2; kf++){
          gi = mfma16(Ah[kf], ld_frag(&swI[(((g     )*2 + kf)*64 + lane)*8]), gi);
          gf = mfma16(Ah[kf], ld_frag(&swI[(((g +  4)*2 + kf)*64 + lane)*8]), gf);
          gg = mfma16(Ah[kf], ld_frag(&swI[(((g +  8)*2 + kf)*64 + lane)*8]), gg);
          go = mfma16(Ah[kf], ld_frag(&swI[(((g + 12)*2 + kf)*64 + lane)*8]), go);
          gi = mfma16(A0[kf], ld_frag(&swH[(((g     )*2 + kf)*64 + lane)*8]), gi);
          gf = mfma16(A0[kf], ld_frag(&swH[(((g +  4)*2 + kf)*64 + lane)*8]), gf);
          gg = mfma16(A0[kf], ld_frag(&swH[(((g +  8)*2 + kf)*64 + lane)*8]), gg);
          go = mfma16(A0[kf], ld_frag(&swH[(((g + 12)*2 + kf)*64 + lane)*8]), go);
        }
        float bi = l_bih[(g     )*16 + ln] + l_bhh[(g     )*16 + ln];
        float bf = l_bih[(g +  4)*16 + ln] + l_bhh[(g +  4)*16 + ln];
        float bg = l_bih[(g +  8)*16 + ln] + l_bhh[(g +  8)*16 + ln];
        float bo = l_bih[(g + 12)*16 + ln] + l_bhh[(g + 12)*16 + ln];
        #pragma unroll
        for(int r = 0; r < 4; r++){
          int row = row0 + q*4 + r, col = g*16 + ln;
          float cp = c0[(size_t)row*64 + col];
          float si = sigm(gi[r] + bi), sf = sigm(gf[r] + bf), so = sigm(go[r] + bo);
          float c1 = sf*cp + si*tanh_fast(gg[r] + bg);
          float h1 = so*tanh_fast(c1);
          c1o[(size_t)row*64 + col] = c1;
          h1o[(size_t)row*64 + col] = h1;
          tile_sh[wid][(q*4 + r)*72 + col] = f2bf(fmaxf(h1, 0.f));
        }
      }
    }
    __syncthreads();
    if(act){
      f32x4 C = {0.f,0.f,0.f,0.f};
      #pragma unroll
      for(int kf = 0; kf < 2; kf++){
        bf16x8 a = ld_frag(&tile_sh[wid][ln*72 + kf*32 + q*8]);
        bf16x8 b = ld_frag(&swL[((kf)*64 + lane)*8]);
        C = mfma16(a, b, C);
      }
      if(ln < 12){
        float lb = lin_b[ln];
        #pragma unroll
        for(int r = 0; r < 4; r++) out[(size_t)(row0 + q*4 + r)*12 + ln] = C[r] + lb;
      }
    }
    __syncthreads();
  }
}

extern "C" void kernel_launch(void* const* d_in, const int* in_sizes, int n_in,
                              void* d_out, int out_size, void* d_ws, size_t ws_size,
                              hipStream_t stream){
  const float* x     = (const float*)d_in[0];
  const float* ew    = (const float*)d_in[1];
  const float* wconv = (const float*)d_in[2];
  const float* gwih  = (const float*)d_in[3];
  const float* gwhh  = (const float*)d_in[4];
  const float* gbih  = (const float*)d_in[5];
  const float* gbhh  = (const float*)d_in[6];
  const float* lwih  = (const float*)d_in[7];
  const float* lwhh  = (const float*)d_in[8];
  const float* lbih  = (const float*)d_in[9];
  const float* lbhh  = (const float*)d_in[10];
  const float* linw  = (const float*)d_in[11];
  const float* linb  = (const float*)d_in[12];
  const float* h0    = (const float*)d_in[13];
  const float* c0    = (const float*)d_in[14];
  const int*   ei    = (const int*)d_in[15];

  char* w = (char*)d_ws;
  size_t o = 0;
  auto alloc = [&](size_t bytes) -> void* {
    void* p = w + o; o += (bytes + 255) & ~(size_t)255; return p;
  };
  unsigned short* xb   = (unsigned short*)alloc((size_t)NN*64*2);
  unsigned short* agg  = (unsigned short*)alloc((size_t)NN*64*2);
  unsigned short* htl  = (unsigned short*)alloc((size_t)NN*64*2);
  unsigned short* Bc   = (unsigned short*)alloc(12288*2);
  unsigned short* bghh = (unsigned short*)alloc(12288*2);
  unsigned short* blih = (unsigned short*)alloc(16384*2);
  unsigned short* blhh = (unsigned short*)alloc(16384*2);
  unsigned short* blin = (unsigned short*)alloc(768*2);
  int* cnt  = (int*)alloc((size_t)NN*4);
  int* off  = (int*)alloc((size_t)NN*4);
  int* bsum = (int*)alloc(512);
  unsigned short* rank = (unsigned short*)alloc((size_t)NE*2);
  int2* spk = (int2*)alloc((size_t)NE*8);

  float* outp = (float*)d_out;
  float* h1o  = outp + (size_t)NN*12;
  float* c1o  = h1o + (size_t)NN*64;

  hipMemsetAsync(cnt, 0, (size_t)NN*4, stream);
  k_prep   <<<512, 256, 0, stream>>>(x, gwhh, lwih, lwhh, linw, wconv, gwih,
                                     xb, bghh, blih, blhh, blin, Bc);
  k_hist   <<<(NE + 255)/256, 256, 0, stream>>>(ei, cnt, rank);
  k_scan1  <<<SCAN_NB, 256, 0, stream>>>(cnt, off, bsum);
  k_scan2  <<<1, 128, 0, stream>>>(bsum);
  k_scan3  <<<(NN + 255)/256, 256, 0, stream>>>(bsum, off);
  k_scatter<<<(NE + 255)/256, 256, 0, stream>>>(ei, ew, off, rank, spk);
  k_spmm   <<<(NN + 3)/4, 256, 0, stream>>>(xb, spk, off, cnt, agg);
  k_gru    <<<GRU_NBLK, 256, 0, stream>>>(agg, xb, Bc, bghh, gbih, gbhh, htl);
  k_lstm   <<<LSTM_NBLK, 256, 0, stream>>>(htl, h0, c0, blih, blhh, lbih, lbhh,
                                           blin, linb, outp, h1o, c1o);
}